// Round 4
// baseline (1458.895 us; speedup 1.0000x reference)
//
#include <hip/hip_runtime.h>
#include <stdint.h>

#define L_SIG   8192
#define T_STEPS 253
#define H1      256
#define H2      128
#define NBATCH  256

typedef __attribute__((ext_vector_type(8))) short short8;
typedef __attribute__((ext_vector_type(4))) float f32x4;
typedef unsigned int uint32x4 __attribute__((ext_vector_type(4)));
typedef unsigned int uint32x2 __attribute__((ext_vector_type(2)));

__device__ __forceinline__ ushort f2bf(float f){
  uint32_t u = __builtin_bit_cast(uint32_t, f);
  u += 0x7FFFu + ((u >> 16) & 1u);
  return (ushort)(u >> 16);
}
__device__ __forceinline__ float bf2f(ushort h){
  uint32_t u = ((uint32_t)h) << 16;
  return __builtin_bit_cast(float, u);
}
__device__ __forceinline__ float sigm(float x){ return 1.0f / (1.0f + __expf(-x)); }
__device__ __forceinline__ float tanhfast(float x){ return 1.0f - 2.0f / (__expf(2.0f*x) + 1.0f); }
// 16B-unit swizzle within sh rows (bijective per 8-unit stripe)
__device__ __forceinline__ int swz(int u){ return u ^ ((u >> 3) & 7); }
// agent-coherent 16B load (MALL-coherent); caller drains vmcnt
__device__ __forceinline__ void load4(uint32x4& r, const unsigned int* p){
  asm volatile("global_load_dwordx4 %0, %1, off sc0 sc1" : "=&v"(r) : "v"(p));
}
// agent-coherent 8B store: (value, tag) published atomically
__device__ __forceinline__ void store2_coh(unsigned int* p, uint32x2 v){
  asm volatile("global_store_dwordx2 %0, %1, off sc0 sc1" :: "v"(p), "v"(v) : "memory");
}

__global__ __launch_bounds__(256, 1)
void encoder_kernel(const float* __restrict__ x,
                    const float* __restrict__ Wih1, const float* __restrict__ Whh1,
                    const float* __restrict__ bih1, const float* __restrict__ bhh1,
                    const float* __restrict__ Wih2, const float* __restrict__ Whh2,
                    const float* __restrict__ bih2, const float* __restrict__ bhh2,
                    float* __restrict__ out,
                    unsigned long long* h1t,      // [2][256][256] (value,tag) u64
                    unsigned long long* h2t)      // [2][256][128] (value,tag) u64
{
  // A operand rows: 16 batches x 520 ushort cols; cols [0,128)=x, [128,384)=h1, [384,512)=h2
  // stored by 16B units: ushort col c -> unit u=c>>3 at ushort offset 8*swz(u)
  __shared__ ushort sh_hi[16][520];
  __shared__ ushort sh_lo[16][520];
  __shared__ float  sC1[4][4][16][20];     // [kq][gate][dim][batch] K-partials
  __shared__ float  sC2[4][2][16][20];     // [kq][tile][row][batch]

  const int tid  = threadIdx.x;
  const int lane = tid & 63;
  const int wv   = tid >> 6;               // wave 0..3 = K-quarter
  const int bid  = blockIdx.x;
  // XCD-aware grouping (perf-only): blocks with equal bid&7 share an XCD.
  const int grp = 2 * (bid & 7) + (bid >> 7);   // 16 groups x 16 batches
  const int bi  = (bid & 127) >> 3;             // block-in-group 0..15
  const int B0  = grp * 16;
  const int D1  = bi * 16;                 // h1-dim slice
  const int D2  = bi * 8;                  // h2-dim slice

  // ------------- persistent W fragments (hi/lo split bf16), K-split tiling -------
  // wave wv owns K-cols 32*(3wv) .. 32*(3wv+3) of each gate/tile
  short8 B1h[12], B1l[12];                 // [gate*3 + i]
  short8 B2h[6],  B2l[6];                  // [tile*3 + i]
  {
    const int nn = lane & 15, p = lane >> 4;
    #pragma unroll
    for (int g = 0; g < 4; ++g){
      const int R1 = g * 256 + D1 + nn;
      #pragma unroll
      for (int i = 0; i < 3; ++i){
        short8 h8, l8;
        #pragma unroll
        for (int j = 0; j < 8; ++j){
          const int k = 32*(3*wv + i) + 8*p + j;
          const float v = (k < 128) ? Wih1[R1*128 + k] : Whh1[R1*256 + (k - 128)];
          const ushort hb = f2bf(v);
          h8[j] = (short)hb;
          l8[j] = (short)f2bf(v - bf2f(hb));
        }
        B1h[g*3 + i] = h8; B1l[g*3 + i] = l8;
      }
    }
    #pragma unroll
    for (int tw = 0; tw < 2; ++tw){
      const int rr = tw*16 + nn;                    // row-in-32 = g2*8 + d2
      const int R2 = (rr >> 3) * 128 + D2 + (rr & 7);
      #pragma unroll
      for (int i = 0; i < 3; ++i){
        short8 h8, l8;
        #pragma unroll
        for (int j = 0; j < 8; ++j){
          const int k = 32*(3*wv + i) + 8*p + j;
          const float v = (k < 256) ? Wih2[R2*256 + k] : Whh2[R2*128 + (k - 256)];
          const ushort hb = f2bf(v);
          h8[j] = (short)hb;
          l8[j] = (short)f2bf(v - bf2f(hb));
        }
        B2h[tw*3 + i] = h8; B2l[tw*3 + i] = l8;
      }
    }
  }

  // biases per epilogue thread
  const int eb  = tid >> 4, ed  = tid & 15;          // LSTM1 (batch, dim)
  const int eb2 = (tid & 127) >> 3, ed2 = tid & 7;   // LSTM2 (tid<128)
  float bs1[4], bs2[4];
  #pragma unroll
  for (int g = 0; g < 4; ++g){
    bs1[g] = bih1[g*256 + D1 + ed]  + bhh1[g*256 + D1 + ed];
    bs2[g] = bih2[g*128 + D2 + ed2] + bhh2[g*128 + D2 + ed2];
  }

  float c1 = 0.f, c2 = 0.f;

  // coalesced x-window stage: 16 batches x 128 cols, 8 floats/thread
  auto stageX = [&](int wn){
    const int bx = tid >> 4, cx = tid & 15;
    const float* xp = x + (size_t)(B0 + bx) * L_SIG + 32*wn + 8*cx;
    const float4 v0 = *(const float4*)xp;
    const float4 v1 = *(const float4*)(xp + 4);
    float f[8] = {v0.x, v0.y, v0.z, v0.w, v1.x, v1.y, v1.z, v1.w};
    union { ushort s[8]; uint32x4 v; } H, L;
    #pragma unroll
    for (int j = 0; j < 8; ++j){
      const ushort hb = f2bf(f[j]);
      H.s[j] = hb;
      L.s[j] = f2bf(f[j] - bf2f(hb));
    }
    const int u = swz(cx);
    *(uint32x4*)&sh_hi[bx][8*u] = H.v;
    *(uint32x4*)&sh_lo[bx][8*u] = L.v;
  };

  // ---------------- prologue: zero state LDS region, stage x(0) ----------------
  {
    uint32x4 z = {0,0,0,0};
    for (int i = tid; i < 16*48; i += 256){
      const int b = i / 48, u = 16 + (i % 48);
      *(uint32x4*)&sh_hi[b][8*swz(u)] = z;
      *(uint32x4*)&sh_lo[b][8*swz(u)] = z;
    }
  }
  stageX(0);
  __syncthreads();

  const int m = lane & 15, p = lane >> 4;

  for (int n = 0; n <= T_STEPS; ++n){
    // ---------------- MFMA phase (K-split across waves) ----------------
    if (n < T_STEPS){                      // LSTM1 step n: K-cols [0,384)
      f32x4 aH[4] = {{0,0,0,0},{0,0,0,0},{0,0,0,0},{0,0,0,0}};
      f32x4 aM[4] = {{0,0,0,0},{0,0,0,0},{0,0,0,0},{0,0,0,0}};
      #pragma unroll
      for (int i = 0; i < 3; ++i){
        const int u = swz(4*(3*wv + i) + p);
        const short8 ah = *(const short8*)&sh_hi[m][8*u];
        const short8 al = *(const short8*)&sh_lo[m][8*u];
        #pragma unroll
        for (int g = 0; g < 4; ++g){
          aH[g] = __builtin_amdgcn_mfma_f32_16x16x32_bf16(ah, B1h[g*3+i], aH[g], 0, 0, 0);
          aM[g] = __builtin_amdgcn_mfma_f32_16x16x32_bf16(ah, B1l[g*3+i], aM[g], 0, 0, 0);
          aM[g] = __builtin_amdgcn_mfma_f32_16x16x32_bf16(al, B1h[g*3+i], aM[g], 0, 0, 0);
        }
      }
      #pragma unroll
      for (int g = 0; g < 4; ++g){
        const f32x4 cs = aH[g] + aM[g];
        *(f32x4*)&sC1[wv][g][m][4*p] = cs;   // b128, batch-contiguous
      }
    }
    if (n >= 1){                           // LSTM2 step n-1: K-cols [128,512)
      f32x4 aH[2] = {{0,0,0,0},{0,0,0,0}};
      f32x4 aM[2] = {{0,0,0,0},{0,0,0,0}};
      #pragma unroll
      for (int i = 0; i < 3; ++i){
        const int u = swz(16 + 4*(3*wv + i) + p);
        const short8 ah = *(const short8*)&sh_hi[m][8*u];
        const short8 al = *(const short8*)&sh_lo[m][8*u];
        #pragma unroll
        for (int tw = 0; tw < 2; ++tw){
          aH[tw] = __builtin_amdgcn_mfma_f32_16x16x32_bf16(ah, B2h[tw*3+i], aH[tw], 0, 0, 0);
          aM[tw] = __builtin_amdgcn_mfma_f32_16x16x32_bf16(ah, B2l[tw*3+i], aM[tw], 0, 0, 0);
          aM[tw] = __builtin_amdgcn_mfma_f32_16x16x32_bf16(al, B2h[tw*3+i], aM[tw], 0, 0, 0);
        }
      }
      #pragma unroll
      for (int tw = 0; tw < 2; ++tw){
        const f32x4 cs = aH[tw] + aM[tw];
        *(f32x4*)&sC2[wv][tw][m][4*p] = cs;
      }
    }
    __syncthreads();                       // (1) sC ready

    // ---------------- epilogues: K-reduce, gate math, tagged publish ----------
    if (n < T_STEPS){
      float gv[4];
      #pragma unroll
      for (int g = 0; g < 4; ++g)
        gv[g] = sC1[0][g][ed][eb] + sC1[1][g][ed][eb]
              + sC1[2][g][ed][eb] + sC1[3][g][ed][eb] + bs1[g];
      c1 = sigm(gv[1])*c1 + sigm(gv[0])*tanhfast(gv[2]);
      const float h = sigm(gv[3])*tanhfast(c1);
      const ushort hb = f2bf(h);
      const ushort lb = f2bf(h - bf2f(hb));
      uint32x2 pv;
      pv[0] = (uint32_t)hb | ((uint32_t)lb << 16);
      pv[1] = (unsigned)(n + 1);           // tag: step+1
      store2_coh((unsigned int*)(h1t + (size_t)(n & 1)*(NBATCH*H1)
                                 + (size_t)(B0 + eb)*H1 + D1 + ed), pv);
    }
    if (n >= 1 && tid < 128){
      float gi = sC2[0][0][ed2][eb2]   + sC2[1][0][ed2][eb2]   + sC2[2][0][ed2][eb2]   + sC2[3][0][ed2][eb2]   + bs2[0];
      float gf = sC2[0][0][8+ed2][eb2] + sC2[1][0][8+ed2][eb2] + sC2[2][0][8+ed2][eb2] + sC2[3][0][8+ed2][eb2] + bs2[1];
      float gg = sC2[0][1][ed2][eb2]   + sC2[1][1][ed2][eb2]   + sC2[2][1][ed2][eb2]   + sC2[3][1][ed2][eb2]   + bs2[2];
      float go = sC2[0][1][8+ed2][eb2] + sC2[1][1][8+ed2][eb2] + sC2[2][1][8+ed2][eb2] + sC2[3][1][8+ed2][eb2] + bs2[3];
      c2 = sigm(gf)*c2 + sigm(gi)*tanhfast(gg);
      const float h = sigm(go)*tanhfast(c2);
      if (n == T_STEPS){
        out[(size_t)(B0 + eb2)*H2 + D2 + ed2] = h;
      } else {
        const ushort hb = f2bf(h);
        const ushort lb = f2bf(h - bf2f(hb));
        uint32x2 pv;
        pv[0] = (uint32_t)hb | ((uint32_t)lb << 16);
        pv[1] = (unsigned)n;               // h2(n-1) tag = n
        store2_coh((unsigned int*)(h2t + (size_t)((n-1) & 1)*(NBATCH*H2)
                                   + (size_t)(B0 + eb2)*H2 + D2 + ed2), pv);
      }
    }

    // ---------------- tag-poll state load (no barrier), overlap stageX --------
    if (n < T_STEPS){
      const unsigned int* q1 = (const unsigned int*)h1t
          + (size_t)(n & 1)*(2*NBATCH*H1) + (size_t)B0*(2*H1) + 4*tid;
      const unsigned int* q2 = (const unsigned int*)h2t
          + (size_t)((n - 1) & 1)*(2*NBATCH*H2) + (size_t)B0*(2*H2) + 4*tid;
      uint32x4 a[8], c[4];
      #pragma unroll
      for (int j = 0; j < 8; ++j) load4(a[j], q1 + 1024*j);
      #pragma unroll
      for (int j = 0; j < 4; ++j) load4(c[j], q2 + 1024*j);
      if (n + 1 < T_STEPS) stageX(n + 1);  // hides poll latency
      asm volatile("s_waitcnt vmcnt(0)" ::: "memory");
      __builtin_amdgcn_sched_barrier(0);
      const unsigned et1 = (unsigned)(n + 1), et2 = (unsigned)n;
      bool ok = true;
      #pragma unroll
      for (int j = 0; j < 8; ++j) ok = ok && (a[j][1] >= et1) && (a[j][3] >= et1);
      #pragma unroll
      for (int j = 0; j < 4; ++j) ok = ok && (c[j][1] >= et2) && (c[j][3] >= et2);
      while (!ok){
        #pragma unroll
        for (int j = 0; j < 8; ++j) load4(a[j], q1 + 1024*j);
        #pragma unroll
        for (int j = 0; j < 4; ++j) load4(c[j], q2 + 1024*j);
        asm volatile("s_waitcnt vmcnt(0)" ::: "memory");
        __builtin_amdgcn_sched_barrier(0);
        ok = true;
        #pragma unroll
        for (int j = 0; j < 8; ++j) ok = ok && (a[j][1] >= et1) && (a[j][3] >= et1);
        #pragma unroll
        for (int j = 0; j < 4; ++j) ok = ok && (c[j][1] >= et2) && (c[j][3] >= et2);
      }
      // unpack to LDS state region (values at [0],[2]; hi=low16, lo=high16)
      {
        const int th = tid >> 7;
        const int d0 = (2*tid) & 255;
        const int off1 = 8*swz(16 + (d0 >> 3)) + (d0 & 7);
        #pragma unroll
        for (int j = 0; j < 8; ++j){
          const uint32_t v0 = a[j][0], v1 = a[j][2];
          *(uint32_t*)&sh_hi[2*j + th][off1] = (v0 & 0xFFFFu) | (v1 << 16);
          *(uint32_t*)&sh_lo[2*j + th][off1] = (v0 >> 16) | (v1 & 0xFFFF0000u);
        }
        const int t6 = (tid >> 6) & 3;
        const int d2 = (2*tid) & 127;
        const int off2 = 8*swz(48 + (d2 >> 3)) + (d2 & 7);
        #pragma unroll
        for (int j = 0; j < 4; ++j){
          const uint32_t v0 = c[j][0], v1 = c[j][2];
          *(uint32_t*)&sh_hi[4*j + t6][off2] = (v0 & 0xFFFFu) | (v1 << 16);
          *(uint32_t*)&sh_lo[4*j + t6][off2] = (v0 >> 16) | (v1 & 0xFFFF0000u);
        }
      }
      __syncthreads();                     // (2) operands staged for iter n+1
    }
  }
}

extern "C" void kernel_launch(void* const* d_in, const int* in_sizes, int n_in,
                              void* d_out, int out_size, void* d_ws, size_t ws_size,
                              hipStream_t stream)
{
  const float* x    = (const float*)d_in[0];
  const float* Wih1 = (const float*)d_in[1];
  const float* Whh1 = (const float*)d_in[2];
  const float* bih1 = (const float*)d_in[3];
  const float* bhh1 = (const float*)d_in[4];
  const float* Wih2 = (const float*)d_in[5];
  const float* Whh2 = (const float*)d_in[6];
  const float* bih2 = (const float*)d_in[7];
  const float* bhh2 = (const float*)d_in[8];

  uint8_t* ws = (uint8_t*)d_ws;
  unsigned long long* h1t = (unsigned long long*)ws;                // 2*256*256*8 = 1 MB
  unsigned long long* h2t = (unsigned long long*)(ws + (1u << 20)); // 2*256*128*8 = 512 KB

  // tags must start at 0 every launch (graph replays re-run this memset)
  hipMemsetAsync(ws, 0, (1u << 20) + (512u << 10), stream);
  encoder_kernel<<<dim3(256), dim3(256), 0, stream>>>(
      x, Wih1, Whh1, bih1, bhh1, Wih2, Whh2, bih2, bhh2,
      (float*)d_out, h1t, h2t);
}

// Round 6
// 845.706 us; speedup vs baseline: 1.7251x; 1.7251x over previous
//
#include <hip/hip_runtime.h>
#include <stdint.h>

#define L_SIG   8192
#define T_STEPS 253
#define H1      256
#define H2      128
#define NBATCH  256

typedef __attribute__((ext_vector_type(8))) short short8;
typedef __attribute__((ext_vector_type(4))) float f32x4;
typedef unsigned int uint32x4 __attribute__((ext_vector_type(4)));
typedef unsigned int uint32x2 __attribute__((ext_vector_type(2)));

__device__ __forceinline__ ushort f2bf(float f){
  uint32_t u = __builtin_bit_cast(uint32_t, f);
  u += 0x7FFFu + ((u >> 16) & 1u);
  return (ushort)(u >> 16);
}
__device__ __forceinline__ float bf2f(ushort h){
  uint32_t u = ((uint32_t)h) << 16;
  return __builtin_bit_cast(float, u);
}
__device__ __forceinline__ float sigm(float x){ return 1.0f / (1.0f + __expf(-x)); }
__device__ __forceinline__ float tanhfast(float x){ return 1.0f - 2.0f / (__expf(2.0f*x) + 1.0f); }
// 16B-unit swizzle within sh rows (bijective per 8-unit stripe)
__device__ __forceinline__ int swz(int u){ return u ^ ((u >> 3) & 7); }
// system-scope 16B load (L1-bypassing, MALL-coherent) — R3-proven; caller drains vmcnt
__device__ __forceinline__ void ld4_coh(uint32x4& r, const unsigned* p){
  asm volatile("global_load_dwordx4 %0, %1, off sc0 sc1" : "=&v"(r) : "v"(p));
}

__global__ __launch_bounds__(256, 1)
void encoder_kernel(const float* __restrict__ x,
                    const float* __restrict__ Wih1, const float* __restrict__ Whh1,
                    const float* __restrict__ bih1, const float* __restrict__ bhh1,
                    const float* __restrict__ Wih2, const float* __restrict__ Whh2,
                    const float* __restrict__ bih2, const float* __restrict__ bhh2,
                    float* __restrict__ out,
                    unsigned* sync_ws,            // 4KB slot area (memset 0 each launch)
                    unsigned* h1buf,              // [2][256][256] packed hi|lo
                    unsigned* h2buf)              // [2][256][128] packed hi|lo
{
  // A operand rows: 16 batches x 520 ushort cols; [0,128)=x, [128,384)=h1, [384,512)=h2
  __shared__ ushort sh_hi[16][520];
  __shared__ ushort sh_lo[16][520];
  __shared__ float  sC1[4][4][16][20];     // [kq][gate][dim][batch] K-partials
  __shared__ float  sC2[4][2][16][20];     // [kq][tile][row][batch]

  const int tid  = threadIdx.x;
  const int lane = tid & 63;
  const int wv   = tid >> 6;               // wave 0..3 = K-quarter
  const int bid  = blockIdx.x;
  // XCD-friendly grouping (perf-only; correctness never depends on placement)
  const int grp = 2 * (bid & 7) + (bid >> 7);   // 16 groups x 16 batches
  const int bi  = (bid & 127) >> 3;             // block-in-group 0..15
  const int B0  = grp * 16;
  const int D1  = bi * 16;                 // h1-dim slice
  const int D2  = bi * 8;                  // h2-dim slice

  // ------------- persistent W fragments (hi/lo split bf16), K-split tiling -------
  // wave wv owns K-cols 96*wv .. 96*wv+95 of every gate/tile
  short8 B1h[12], B1l[12];                 // [gate*3 + i]
  short8 B2h[6],  B2l[6];                  // [tile*3 + i]
  {
    const int nn = lane & 15, p = lane >> 4;
    #pragma unroll
    for (int g = 0; g < 4; ++g){
      const int R1 = g * 256 + D1 + nn;
      #pragma unroll
      for (int i = 0; i < 3; ++i){
        short8 h8, l8;
        #pragma unroll
        for (int j = 0; j < 8; ++j){
          const int k = 32*(3*wv + i) + 8*p + j;
          const float v = (k < 128) ? Wih1[R1*128 + k] : Whh1[R1*256 + (k - 128)];
          const ushort hb = f2bf(v);
          h8[j] = (short)hb;
          l8[j] = (short)f2bf(v - bf2f(hb));
        }
        B1h[g*3 + i] = h8; B1l[g*3 + i] = l8;
      }
    }
    #pragma unroll
    for (int tw = 0; tw < 2; ++tw){
      const int rr = tw*16 + nn;                    // row-in-32 = g2*8 + d2
      const int R2 = (rr >> 3) * 128 + D2 + (rr & 7);
      #pragma unroll
      for (int i = 0; i < 3; ++i){
        short8 h8, l8;
        #pragma unroll
        for (int j = 0; j < 8; ++j){
          const int k = 32*(3*wv + i) + 8*p + j;
          const float v = (k < 256) ? Wih2[R2*256 + k] : Whh2[R2*128 + (k - 256)];
          const ushort hb = f2bf(v);
          h8[j] = (short)hb;
          l8[j] = (short)f2bf(v - bf2f(hb));
        }
        B2h[tw*3 + i] = h8; B2l[tw*3 + i] = l8;
      }
    }
  }

  // biases per epilogue thread
  const int eb  = tid >> 4, ed  = tid & 15;          // LSTM1 (batch, dim)
  const int eb2 = (tid & 127) >> 3, ed2 = tid & 7;   // LSTM2 (tid<128)
  float bs1[4], bs2[4];
  #pragma unroll
  for (int g = 0; g < 4; ++g){
    bs1[g] = bih1[g*256 + D1 + ed]  + bhh1[g*256 + D1 + ed];
    bs2[g] = bih2[g*128 + D2 + ed2] + bhh2[g*128 + D2 + ed2];
  }

  float c1 = 0.f, c2 = 0.f;                // cell states in registers
  unsigned* slots = sync_ws + grp * 64;    // 16 dwords per group (one cache line)

  // coalesced x-window stage: 16 batches x 128 cols, 8 floats/thread
  auto stageX = [&](int wn){
    const int bx = tid >> 4, cx = tid & 15;
    const float* xp = x + (size_t)(B0 + bx) * L_SIG + 32*wn + 8*cx;
    const float4 v0 = *(const float4*)xp;
    const float4 v1 = *(const float4*)(xp + 4);
    float f[8] = {v0.x, v0.y, v0.z, v0.w, v1.x, v1.y, v1.z, v1.w};
    union { ushort s[8]; uint32x4 v; } H, L;
    #pragma unroll
    for (int j = 0; j < 8; ++j){
      const ushort hb = f2bf(f[j]);
      H.s[j] = hb;
      L.s[j] = f2bf(f[j] - bf2f(hb));
    }
    const int u = swz(cx);
    *(uint32x4*)&sh_hi[bx][8*u] = H.v;
    *(uint32x4*)&sh_lo[bx][8*u] = L.v;
  };

  auto wrState = [&](uint32x4 q, int b, int us){
    union { ushort s[4]; uint32x2 v; } Hh, Ll;
    #pragma unroll
    for (int k = 0; k < 4; ++k){
      const unsigned u = q[k];
      Hh.s[k] = (ushort)(u & 0xFFFFu);
      Ll.s[k] = (ushort)(u >> 16);
    }
    *(uint32x2*)&sh_hi[b][us] = Hh.v;
    *(uint32x2*)&sh_lo[b][us] = Ll.v;
  };

  // coalesced state load: h1(n) parity n&1, h2(n-1) parity (n-1)&1 — loaded ONCE
  auto stageState = [&](int n){
    const unsigned* h1p = h1buf + (size_t)(n & 1)*(NBATCH*H1) + (size_t)B0*H1 + 4*tid;
    uint32x4 q0, q1, q2, q3, q4, q5;
    ld4_coh(q0, h1p);
    ld4_coh(q1, h1p + 1024);
    ld4_coh(q2, h1p + 2048);
    ld4_coh(q3, h1p + 3072);
    const bool h2v = (n >= 1);
    if (h2v){
      const unsigned* h2p = h2buf + (size_t)((n-1) & 1)*(NBATCH*H2) + (size_t)B0*H2 + 4*tid;
      ld4_coh(q4, h2p);
      ld4_coh(q5, h2p + 1024);
    }
    asm volatile("s_waitcnt vmcnt(0)" ::: "memory");
    __builtin_amdgcn_sched_barrier(0);
    {
      const int t6 = tid & 63;
      const int us = 8*swz(16 + (t6 >> 1)) + 4*(t6 & 1);   // h1 cols 128+4*t6
      const int b0r = tid >> 6;
      wrState(q0, b0r + 0,  us);
      wrState(q1, b0r + 4,  us);
      wrState(q2, b0r + 8,  us);
      wrState(q3, b0r + 12, us);
    }
    {
      const int t5 = tid & 31;
      const int us = 8*swz(48 + (t5 >> 1)) + 4*(t5 & 1);   // h2 cols 384+4*t5
      const int b0r = tid >> 5;
      if (h2v){
        wrState(q4, b0r + 0, us);
        wrState(q5, b0r + 8, us);
      } else {
        uint32x2 z = {0, 0};
        *(uint32x2*)&sh_hi[b0r + 0][us] = z; *(uint32x2*)&sh_lo[b0r + 0][us] = z;
        *(uint32x2*)&sh_hi[b0r + 8][us] = z; *(uint32x2*)&sh_lo[b0r + 8][us] = z;
      }
    }
  };

  // ---------------- prologue: zero state LDS region, stage x(0) ----------------
  {
    uint32x4 z = {0,0,0,0};
    for (int i = tid; i < 16*48; i += 256){
      const int b = i / 48, u = 16 + (i % 48);
      *(uint32x4*)&sh_hi[b][8*swz(u)] = z;
      *(uint32x4*)&sh_lo[b][8*swz(u)] = z;
    }
  }
  stageX(0);
  __syncthreads();

  const int m = lane & 15, p = lane >> 4;

  for (int n = 0; n <= T_STEPS; ++n){
    // ---------------- MFMA phase (K-split across waves) ----------------
    if (n < T_STEPS){                      // LSTM1 step n: K-cols [0,384)
      f32x4 aH[4] = {{0,0,0,0},{0,0,0,0},{0,0,0,0},{0,0,0,0}};
      f32x4 aM[4] = {{0,0,0,0},{0,0,0,0},{0,0,0,0},{0,0,0,0}};
      #pragma unroll
      for (int i = 0; i < 3; ++i){
        const int u = swz(4*(3*wv + i) + p);
        const short8 ah = *(const short8*)&sh_hi[m][8*u];
        const short8 al = *(const short8*)&sh_lo[m][8*u];
        #pragma unroll
        for (int g = 0; g < 4; ++g){
          aH[g] = __builtin_amdgcn_mfma_f32_16x16x32_bf16(ah, B1h[g*3+i], aH[g], 0, 0, 0);
          aM[g] = __builtin_amdgcn_mfma_f32_16x16x32_bf16(ah, B1l[g*3+i], aM[g], 0, 0, 0);
          aM[g] = __builtin_amdgcn_mfma_f32_16x16x32_bf16(al, B1h[g*3+i], aM[g], 0, 0, 0);
        }
      }
      #pragma unroll
      for (int g = 0; g < 4; ++g){
        const f32x4 cs = aH[g] + aM[g];
        *(f32x4*)&sC1[wv][g][m][4*p] = cs;   // b128, batch-contiguous
      }
    }
    if (n >= 1){                           // LSTM2 step n-1: K-cols [128,512)
      f32x4 aH[2] = {{0,0,0,0},{0,0,0,0}};
      f32x4 aM[2] = {{0,0,0,0},{0,0,0,0}};
      #pragma unroll
      for (int i = 0; i < 3; ++i){
        const int u = swz(16 + 4*(3*wv + i) + p);
        const short8 ah = *(const short8*)&sh_hi[m][8*u];
        const short8 al = *(const short8*)&sh_lo[m][8*u];
        #pragma unroll
        for (int tw = 0; tw < 2; ++tw){
          aH[tw] = __builtin_amdgcn_mfma_f32_16x16x32_bf16(ah, B2h[tw*3+i], aH[tw], 0, 0, 0);
          aM[tw] = __builtin_amdgcn_mfma_f32_16x16x32_bf16(ah, B2l[tw*3+i], aM[tw], 0, 0, 0);
          aM[tw] = __builtin_amdgcn_mfma_f32_16x16x32_bf16(al, B2h[tw*3+i], aM[tw], 0, 0, 0);
        }
      }
      #pragma unroll
      for (int tw = 0; tw < 2; ++tw){
        const f32x4 cs = aH[tw] + aM[tw];
        *(f32x4*)&sC2[wv][tw][m][4*p] = cs;
      }
    }
    __syncthreads();                       // (1) sC ready

    // ---------------- epilogues: K-reduce, gate math, agent-scope publish ------
    if (n < T_STEPS){
      float gv[4];
      #pragma unroll
      for (int g = 0; g < 4; ++g)
        gv[g] = sC1[0][g][ed][eb] + sC1[1][g][ed][eb]
              + sC1[2][g][ed][eb] + sC1[3][g][ed][eb] + bs1[g];
      c1 = sigm(gv[1])*c1 + sigm(gv[0])*tanhfast(gv[2]);
      const float h = sigm(gv[3])*tanhfast(c1);
      const ushort hb = f2bf(h);
      const ushort lb = f2bf(h - bf2f(hb));
      __hip_atomic_store(
          &h1buf[(size_t)(n & 1)*(NBATCH*H1) + (size_t)(B0 + eb)*H1 + D1 + ed],
          (uint32_t)hb | ((uint32_t)lb << 16),
          __ATOMIC_RELAXED, __HIP_MEMORY_SCOPE_AGENT);
    }
    if (n >= 1 && tid < 128){
      float gi = sC2[0][0][ed2][eb2]   + sC2[1][0][ed2][eb2]   + sC2[2][0][ed2][eb2]   + sC2[3][0][ed2][eb2]   + bs2[0];
      float gf = sC2[0][0][8+ed2][eb2] + sC2[1][0][8+ed2][eb2] + sC2[2][0][8+ed2][eb2] + sC2[3][0][8+ed2][eb2] + bs2[1];
      float gg = sC2[0][1][ed2][eb2]   + sC2[1][1][ed2][eb2]   + sC2[2][1][ed2][eb2]   + sC2[3][1][ed2][eb2]   + bs2[2];
      float go = sC2[0][1][8+ed2][eb2] + sC2[1][1][8+ed2][eb2] + sC2[2][1][8+ed2][eb2] + sC2[3][1][8+ed2][eb2] + bs2[3];
      c2 = sigm(gf)*c2 + sigm(gi)*tanhfast(gg);
      const float h = sigm(go)*tanhfast(c2);
      if (n == T_STEPS){
        out[(size_t)(B0 + eb2)*H2 + D2 + ed2] = h;
      } else {
        const ushort hb = f2bf(h);
        const ushort lb = f2bf(h - bf2f(hb));
        __hip_atomic_store(
            &h2buf[(size_t)((n-1) & 1)*(NBATCH*H2) + (size_t)(B0 + eb2)*H2 + D2 + ed2],
            (uint32_t)hb | ((uint32_t)lb << 16),
            __ATOMIC_RELAXED, __HIP_MEMORY_SCOPE_AGENT);
      }
    }

    // ---------------- slot barrier + prefetch next operands ----------------
    if (n < T_STEPS){
      asm volatile("s_waitcnt vmcnt(0)" ::: "memory");  // publishes at coherence point
      __syncthreads();                     // (2) all waves drained
      if (tid == 0){
        __hip_atomic_store(&slots[bi], (unsigned)(n + 1),
                           __ATOMIC_RELAXED, __HIP_MEMORY_SCOPE_AGENT);
      }
      if (n + 1 < T_STEPS) stageX(n + 1);  // barrier-independent, overlaps the poll
      if (wv == 0){                        // wave0 polls all 16 slots (one line)
        const unsigned tgt = (unsigned)(n + 1);
        for (;;){
          const unsigned v = __hip_atomic_load(&slots[lane & 15],
                                               __ATOMIC_RELAXED, __HIP_MEMORY_SCOPE_AGENT);
          if (__all(v >= tgt)) break;
          __builtin_amdgcn_s_sleep(1);
        }
      }
      __syncthreads();                     // (3) barrier established
      stageState(n);                       // payload loaded exactly once
      __syncthreads();                     // (4) operands staged for iter n+1
    }
  }
}

extern "C" void kernel_launch(void* const* d_in, const int* in_sizes, int n_in,
                              void* d_out, int out_size, void* d_ws, size_t ws_size,
                              hipStream_t stream)
{
  const float* x    = (const float*)d_in[0];
  const float* Wih1 = (const float*)d_in[1];
  const float* Whh1 = (const float*)d_in[2];
  const float* bih1 = (const float*)d_in[3];
  const float* bhh1 = (const float*)d_in[4];
  const float* Wih2 = (const float*)d_in[5];
  const float* Whh2 = (const float*)d_in[6];
  const float* bih2 = (const float*)d_in[7];
  const float* bhh2 = (const float*)d_in[8];

  uint8_t*  ws    = (uint8_t*)d_ws;
  unsigned* syncp = (unsigned*)ws;                          // 4 KB slot area
  unsigned* h1buf = (unsigned*)(ws + 4096);                 // 512 KB
  unsigned* h2buf = (unsigned*)(ws + 4096 + 2*NBATCH*H1*4); // 256 KB

  // slots must start at 0 every launch (graph replays re-run this memset)
  hipMemsetAsync(syncp, 0, 4096, stream);
  encoder_kernel<<<dim3(256), dim3(256), 0, stream>>>(
      x, Wih1, Whh1, bih1, bhh1, Wih2, Whh2, bih2, bhh2,
      (float*)d_out, syncp, h1buf, h2buf);
}